// Round 3
// baseline (1232.600 us; speedup 1.0000x reference)
//
#include <hip/hip_runtime.h>
#include <hip/hip_bf16.h>

// GCN 2-layer: out = (Â relu(Â (x@W1) + b1)) @ W2 + b2,  Â = D^-1/2 (A+I) D^-1/2
// N=100000, E=3200000, dims 128 -> 32 -> 16, fp32.
// Round 3: destination-window binning (128 nodes/bucket) + LDS-tile aggregation.
//   - bin_fill: LDS histogram + one global reservation per (block,bucket)
//     -> run-contiguous record writes (kills fill_csr's 194 MB write-allocate)
//   - deg from binned records (kills count_dst's global atomics)
//   - agg via LDS atomicAdd into a 128xC fp32 tile (kills all global fp32 atomics)

#define IN_DIM 128
#define HID1 32
#define HID2 16

#define W 128           // nodes per destination window
#define WSHIFT 7
#define WMASK 127
#define CAP 4608        // slots per bucket: E/B=4092, sigma=64 -> 8 sigma slack
#define MAXB 800        // >= ceil(100000/128)=782
#define CHUNK 8192      // edges per bin_fill block

// ---------------------------------------------------------------------------
// Edge dtype probe (reference says int64; default JAX gives int32).
__global__ void detect_fmt(const int* __restrict__ e32, int* __restrict__ flag) {
    if (blockIdx.x == 0 && threadIdx.x == 0) {
        int is64 = 1;
        for (int i = 0; i < 64; ++i)
            if (e32[2 * i + 1] != 0) { is64 = 0; break; }
        *flag = is64;
    }
}

__device__ __forceinline__ void load_edge(const int* __restrict__ e32, int is64,
                                          long e, long E, int& s, int& d) {
    if (is64) { s = e32[2 * e];  d = e32[2 * E + 2 * e]; }
    else      { s = e32[e];      d = e32[E + e]; }
}

// ---------------------------------------------------------------------------
__global__ void init_cursor(int* __restrict__ gCursor, int B) {
    int b = blockIdx.x * blockDim.x + threadIdx.x;
    if (b < B) gCursor[b] = b * CAP;
}

// Bin edges into destination windows. packed rec = (src << 7) | (dst & 127).
__global__ __launch_bounds__(256) void bin_fill(const int* __restrict__ e32,
                                                const int* __restrict__ flag,
                                                int* __restrict__ gCursor,
                                                int* __restrict__ packed,
                                                long E, int B) {
    __shared__ int hist[MAXB];
    __shared__ int gcur[MAXB];
    int is64 = *flag;
    long base = (long)blockIdx.x * CHUNK;
    int count = (int)min((long)CHUNK, E - base);

    for (int i = threadIdx.x; i < B; i += 256) hist[i] = 0;
    __syncthreads();

    // phase 1: local histogram
    for (int i = threadIdx.x; i < count; i += 256) {
        int s, d;
        load_edge(e32, is64, base + i, E, s, d);
        atomicAdd(&hist[d >> WSHIFT], 1);
    }
    __syncthreads();

    // phase 2: reserve a contiguous run per bucket
    for (int i = threadIdx.x; i < B; i += 256) {
        int h = hist[i];
        gcur[i] = h ? atomicAdd(&gCursor[i], h) : 0;
    }
    __syncthreads();

    // phase 3: re-read (L2-hot) and write run-contiguous
    for (int i = threadIdx.x; i < count; i += 256) {
        int s, d;
        load_edge(e32, is64, base + i, E, s, d);
        int b = d >> WSHIFT;
        int pos = atomicAdd(&gcur[b], 1);   // LDS atomic -> contiguous global slots
        packed[pos] = (s << WSHIFT) | (d & WMASK);
    }
}

// Per-window degree count -> inv = rsqrt(deg + 1)
__global__ __launch_bounds__(256) void deg_k(const int* __restrict__ gCursor,
                                             const int* __restrict__ packed,
                                             float* __restrict__ inv, int N) {
    __shared__ int dcnt[W];
    int b = blockIdx.x;
    int start = b * CAP;
    int cnt = gCursor[b] - start;
    if (threadIdx.x < W) dcnt[threadIdx.x] = 0;
    __syncthreads();
    for (int i = threadIdx.x; i < cnt; i += 256)
        atomicAdd(&dcnt[packed[start + i] & WMASK], 1);
    __syncthreads();
    if (threadIdx.x < W) {
        int n = b * W + threadIdx.x;
        if (n < N) inv[n] = rsqrtf((float)(dcnt[threadIdx.x] + 1));
    }
}

// ---------------------------------------------------------------------------
// xw = x @ W1   (x: [N,128], W1: [128,32])
__global__ __launch_bounds__(256) void gemm1(const float* __restrict__ x,
                                             const float* __restrict__ W1,
                                             float* __restrict__ xw, int N) {
    __shared__ float sW[IN_DIM * HID1];  // 16 KB
    __shared__ float sX[8 * IN_DIM];     // 4 KB
    for (int i = threadIdx.x; i < IN_DIM * HID1 / 4; i += 256)
        ((float4*)sW)[i] = ((const float4*)W1)[i];

    int row0 = blockIdx.x * 8;
    {
        int rr = threadIdx.x / 32;
        int kk = (threadIdx.x % 32) * 4;
        int grow = row0 + rr;
        float4 v = make_float4(0.f, 0.f, 0.f, 0.f);
        if (grow < N) v = *(const float4*)&x[(size_t)grow * IN_DIM + kk];
        *(float4*)&sX[rr * IN_DIM + kk] = v;
    }
    __syncthreads();

    int col = threadIdx.x % HID1;
    int lr  = threadIdx.x / HID1;
    int grow = row0 + lr;
    if (grow >= N) return;
    float acc = 0.f;
#pragma unroll
    for (int k = 0; k < IN_DIM; ++k)
        acc += sX[lr * IN_DIM + k] * sW[k * HID1 + col];
    xw[(size_t)grow * HID1 + col] = acc;
}

// ---------------------------------------------------------------------------
// Layer-1 aggregate: one block per window; LDS tile 128x32 fp32 (16 KB).
// agg1[n][c] = relu( b1[c] + inv[n] * ( tile[n][c] + xw[n][c]*inv[n] ) )
__global__ __launch_bounds__(512) void agg1_k(const int* __restrict__ gCursor,
                                              const int* __restrict__ packed,
                                              const float* __restrict__ inv,
                                              const float* __restrict__ xw,
                                              const float* __restrict__ b1,
                                              float* __restrict__ agg1, int N) {
    __shared__ float tile[W * HID1];     // 16 KB
    int b = blockIdx.x;
    int start = b * CAP;
    int cnt = gCursor[b] - start;

    for (int i = threadIdx.x; i < W * HID1; i += 512) tile[i] = 0.f;
    __syncthreads();

    int lane = threadIdx.x & 63;
    int wv   = threadIdx.x >> 6;        // 0..7
    int c    = lane & 31;
    int half = lane >> 5;               // 0/1
    // 16 edges per block-iteration (8 waves x 2 halves)
    for (int i = wv * 2 + half; i < cnt; i += 16) {
        int rec = packed[start + i];
        int s  = rec >> WSHIFT;
        int dl = rec & WMASK;
        float v = xw[(size_t)s * HID1 + c] * inv[s];
        atomicAdd(&tile[dl * HID1 + c], v);   // bank = c -> conflict-free
    }
    __syncthreads();

    for (int i = threadIdx.x; i < W * HID1; i += 512) {
        int r = i >> 5, cc = i & 31;
        int n = b * W + r;
        if (n < N) {
            float ivn = inv[n];
            float v = b1[cc] + ivn * (tile[i] + xw[(size_t)n * HID1 + cc] * ivn);
            agg1[(size_t)n * HID1 + cc] = fmaxf(v, 0.f);   // ReLU folded
        }
    }
}

// hw = agg1 @ W2   (agg1 already ReLU'd; [N,32] @ [32,16])
__global__ __launch_bounds__(256) void gemm2(const float* __restrict__ h,
                                             const float* __restrict__ W2,
                                             float* __restrict__ hw, int N) {
    __shared__ float sW[HID1 * HID2];  // 2 KB
    for (int i = threadIdx.x; i < HID1 * HID2; i += 256) sW[i] = W2[i];
    __syncthreads();

    int col = threadIdx.x % HID2;
    int lr  = threadIdx.x / HID2;  // 16 rows per block
    int grow = blockIdx.x * 16 + lr;
    if (grow >= N) return;
    float acc = 0.f;
#pragma unroll
    for (int c = 0; c < HID1; ++c)
        acc += h[(size_t)grow * HID1 + c] * sW[c * HID2 + col];
    hw[(size_t)grow * HID2 + col] = acc;
}

// Layer-2 aggregate: LDS tile 128x16 fp32 (8 KB); 32 edges / block-iter.
__global__ __launch_bounds__(512) void agg2_k(const int* __restrict__ gCursor,
                                              const int* __restrict__ packed,
                                              const float* __restrict__ inv,
                                              const float* __restrict__ hw,
                                              const float* __restrict__ b2,
                                              float* __restrict__ out, int N) {
    __shared__ float tile[W * HID2];     // 8 KB
    int b = blockIdx.x;
    int start = b * CAP;
    int cnt = gCursor[b] - start;

    for (int i = threadIdx.x; i < W * HID2; i += 512) tile[i] = 0.f;
    __syncthreads();

    int lane = threadIdx.x & 63;
    int wv   = threadIdx.x >> 6;        // 0..7
    int c    = lane & 15;
    int q    = lane >> 4;               // 0..3
    for (int i = wv * 4 + q; i < cnt; i += 32) {
        int rec = packed[start + i];
        int s  = rec >> WSHIFT;
        int dl = rec & WMASK;
        float v = hw[(size_t)s * HID2 + c] * inv[s];
        atomicAdd(&tile[dl * HID2 + c], v);
    }
    __syncthreads();

    for (int i = threadIdx.x; i < W * HID2; i += 512) {
        int r = i >> 4, cc = i & 15;
        int n = b * W + r;
        if (n < N) {
            float ivn = inv[n];
            out[(size_t)n * HID2 + cc] =
                b2[cc] + ivn * (tile[i] + hw[(size_t)n * HID2 + cc] * ivn);
        }
    }
}

// ---------------------------------------------------------------------------
extern "C" void kernel_launch(void* const* d_in, const int* in_sizes, int n_in,
                              void* d_out, int out_size, void* d_ws, size_t ws_size,
                              hipStream_t stream) {
    const float* x  = (const float*)d_in[0];
    const float* W1 = (const float*)d_in[1];
    const float* b1 = (const float*)d_in[2];
    const float* W2 = (const float*)d_in[3];
    const float* b2 = (const float*)d_in[4];
    const int*  e32 = (const int*)d_in[5];
    float* out = (float*)d_out;

    const int N = in_sizes[0] / IN_DIM;   // 100000
    const long E = in_sizes[5] / 2;       // 3200000
    const int B = (N + W - 1) >> WSHIFT;  // 782

    // workspace layout
    char* ws = (char*)d_ws;
    int*   flag    = (int*)ws;                         // 1
    int*   gCursor = (int*)(ws + 256);                 // B
    float* inv     = (float*)(gCursor + ((B + 63) / 64) * 64);  // N
    int*   packed  = (int*)(inv + ((N + 63) / 64) * 64);        // (B+1)*CAP ~ 14.4 MB
    float* xw      = (float*)(packed + (size_t)(B + 1) * CAP);  // N*32
    float* agg1    = xw + (size_t)N * HID1;            // N*32
    float* hw      = xw;                               // alias: xw dead after agg1_k

    detect_fmt<<<1, 64, 0, stream>>>(e32, flag);
    init_cursor<<<(B + 255) / 256, 256, 0, stream>>>(gCursor, B);
    bin_fill<<<(int)((E + CHUNK - 1) / CHUNK), 256, 0, stream>>>(e32, flag, gCursor, packed, E, B);
    deg_k<<<B, 256, 0, stream>>>(gCursor, packed, inv, N);

    gemm1<<<(N + 7) / 8, 256, 0, stream>>>(x, W1, xw, N);
    agg1_k<<<B, 512, 0, stream>>>(gCursor, packed, inv, xw, b1, agg1, N);

    gemm2<<<(N + 15) / 16, 256, 0, stream>>>(agg1, W2, hw, N);
    agg2_k<<<B, 512, 0, stream>>>(gCursor, packed, inv, hw, b2, out, N);
}

// Round 6
// 1089.863 us; speedup vs baseline: 1.1310x; 1.1310x over previous
//
#include <hip/hip_runtime.h>
#include <hip/hip_bf16.h>

// GCN 2-layer: out = (Â relu(Â (x@W1) + b1)) @ W2 + b2,  Â = D^-1/2 (A+I) D^-1/2
// N=100000, E=3200000, dims 128 -> 32 -> 16, fp32.
// Round 6: round-5 structure with the self-loop fix. xws/hws are PRESCALED by
// inv[row], so the self term in each epilogue is (tile + xws[n]) * inv[n] --
// rounds 4/5 wrongly multiplied the self term by inv again (xw*inv^3).

#define IN_DIM 128
#define HID1 32
#define HID2 16

#define W 64            // nodes per destination window
#define WSHIFT 6
#define WMASK 63
#define CAP 2560        // slots/bucket: mean 2048, sigma 45 -> 11 sigma slack
#define MAXB 1600       // >= ceil(100000/64)=1563
#define NB_FILL 256     // persistent blocks for bin_fill

// ---------------------------------------------------------------------------
// Edge dtype probe (reference says int64; default JAX gives int32).
__global__ void detect_fmt(const int* __restrict__ e32, int* __restrict__ flag) {
    if (blockIdx.x == 0 && threadIdx.x == 0) {
        int is64 = 1;
        for (int i = 0; i < 64; ++i)
            if (e32[2 * i + 1] != 0) { is64 = 0; break; }
        *flag = is64;
    }
}

__device__ __forceinline__ void load_edge(const int* __restrict__ e32, int is64,
                                          long e, long E, int& s, int& d) {
    if (is64) { s = e32[2 * e];  d = e32[2 * E + 2 * e]; }
    else      { s = e32[e];      d = e32[E + e]; }
}

__device__ __forceinline__ int load_dst(const int* __restrict__ e32, int is64,
                                        long e, long E) {
    return is64 ? e32[2 * E + 2 * e] : e32[E + e];
}

// ---------------------------------------------------------------------------
__global__ void init_cursor(int* __restrict__ gCursor, int B) {
    int b = blockIdx.x * blockDim.x + threadIdx.x;
    if (b < B) gCursor[b] = b * CAP;
}

// Bin edges into dst windows. rec = (src << 6) | (dst & 63).
__global__ __launch_bounds__(512) void bin_fill(const int* __restrict__ e32,
                                                const int* __restrict__ flag,
                                                int* __restrict__ gCursor,
                                                int* __restrict__ packed,
                                                long E, int B) {
    __shared__ int hist[MAXB];
    __shared__ int gcur[MAXB];
    int is64 = *flag;
    long chunk = (E + NB_FILL - 1) / NB_FILL;
    long base = (long)blockIdx.x * chunk;
    if (base >= E) return;
    int count = (int)min(chunk, E - base);

    for (int i = threadIdx.x; i < B; i += 512) hist[i] = 0;
    __syncthreads();

    for (int i = threadIdx.x; i < count; i += 512) {
        int d = load_dst(e32, is64, base + i, E);
        atomicAdd(&hist[d >> WSHIFT], 1);
    }
    __syncthreads();

    for (int i = threadIdx.x; i < B; i += 512) {
        int h = hist[i];
        gcur[i] = h ? atomicAdd(&gCursor[i], h) : 0;
    }
    __syncthreads();

    for (int i = threadIdx.x; i < count; i += 512) {
        int s, d;
        load_edge(e32, is64, base + i, E, s, d);
        int b = d >> WSHIFT;
        int pos = atomicAdd(&gcur[b], 1);
        packed[pos] = (s << WSHIFT) | (d & WMASK);
    }
}

// Per-window degree count -> inv = rsqrt(deg + 1)
__global__ __launch_bounds__(256) void deg_k(const int* __restrict__ gCursor,
                                             const int* __restrict__ packed,
                                             float* __restrict__ inv, int N) {
    __shared__ int dcnt[W];
    int b = blockIdx.x;
    int start = b * CAP;
    int cnt = gCursor[b] - start;
    if (threadIdx.x < W) dcnt[threadIdx.x] = 0;
    __syncthreads();
    for (int i = threadIdx.x; i < cnt; i += 256)
        atomicAdd(&dcnt[packed[start + i] & WMASK], 1);
    __syncthreads();
    if (threadIdx.x < W) {
        int n = b * W + threadIdx.x;
        if (n < N) inv[n] = rsqrtf((float)(dcnt[threadIdx.x] + 1));
    }
}

// ---------------------------------------------------------------------------
// xws = (x @ W1) * inv[row]
__global__ __launch_bounds__(256) void gemm1(const float* __restrict__ x,
                                             const float* __restrict__ W1,
                                             const float* __restrict__ inv,
                                             float* __restrict__ xws, int N) {
    __shared__ float sW[IN_DIM * HID1];  // 16 KB
    __shared__ float sX[8 * IN_DIM];     // 4 KB
    for (int i = threadIdx.x; i < IN_DIM * HID1 / 4; i += 256)
        ((float4*)sW)[i] = ((const float4*)W1)[i];

    int row0 = blockIdx.x * 8;
    {
        int rr = threadIdx.x / 32;
        int kk = (threadIdx.x % 32) * 4;
        int grow = row0 + rr;
        float4 v = make_float4(0.f, 0.f, 0.f, 0.f);
        if (grow < N) v = *(const float4*)&x[(size_t)grow * IN_DIM + kk];
        *(float4*)&sX[rr * IN_DIM + kk] = v;
    }
    __syncthreads();

    int col = threadIdx.x % HID1;
    int lr  = threadIdx.x / HID1;
    int grow = row0 + lr;
    if (grow >= N) return;
    float acc = 0.f;
#pragma unroll
    for (int k = 0; k < IN_DIM; ++k)
        acc += sX[lr * IN_DIM + k] * sW[k * HID1 + col];
    xws[(size_t)grow * HID1 + col] = acc * inv[grow];
}

// ---------------------------------------------------------------------------
// Layer-1 aggregate + FUSED layer-2 transform.
//   tile <- sum of prescaled neighbor feats (LDS atomics, 4-deep pipeline)
//   tile <- relu(b1 + inv[n]*(tile + xws[n]))   [xws already carries inv[n]]
//   hws[n] <- (tile_row @ W2) * inv[n]
__global__ __launch_bounds__(256) void agg1_k(const int* __restrict__ gCursor,
                                              const int* __restrict__ packed,
                                              const float* __restrict__ inv,
                                              const float* __restrict__ xws,
                                              const float* __restrict__ b1,
                                              const float* __restrict__ W2,
                                              float* __restrict__ hws, int N) {
    __shared__ float tile[W * HID1];       // 8 KB
    __shared__ float sW2[HID1 * HID2];     // 2 KB
    int b = blockIdx.x;
    int start = b * CAP;
    int cnt = gCursor[b] - start;

    for (int i = threadIdx.x; i < W * HID1; i += 256) tile[i] = 0.f;
    for (int i = threadIdx.x; i < HID1 * HID2; i += 256) sW2[i] = W2[i];
    __syncthreads();

    int lane = threadIdx.x & 63;
    int wv   = threadIdx.x >> 6;        // 0..3
    int c    = lane & 31;
    int half = lane >> 5;               // 0/1
    // starts 0..7, stride 32, 4 accesses at +0/+8/+16/+24: each index once
    for (int i = 2 * wv + half; i < cnt; i += 32) {
        int ib = i + 8, ic = i + 16, id = i + 24;
        bool vb = ib < cnt, vc = ic < cnt, vd = id < cnt;
        int ra = packed[start + i];
        int rb = packed[start + (vb ? ib : 0)];
        int rc = packed[start + (vc ? ic : 0)];
        int rd = packed[start + (vd ? id : 0)];
        float fa = xws[(size_t)(ra >> WSHIFT) * HID1 + c];
        float fb = xws[(size_t)(rb >> WSHIFT) * HID1 + c];
        float fc = xws[(size_t)(rc >> WSHIFT) * HID1 + c];
        float fd = xws[(size_t)(rd >> WSHIFT) * HID1 + c];
        atomicAdd(&tile[(ra & WMASK) * HID1 + c], fa);
        atomicAdd(&tile[(rb & WMASK) * HID1 + c], vb ? fb : 0.f);
        atomicAdd(&tile[(rc & WMASK) * HID1 + c], vc ? fc : 0.f);
        atomicAdd(&tile[(rd & WMASK) * HID1 + c], vd ? fd : 0.f);
    }
    __syncthreads();

    // h = relu(b1 + inv[n]*(agg + xws_self))  -- FIX: no extra *inv on self
    for (int i = threadIdx.x; i < W * HID1; i += 256) {
        int r = i >> 5, cc = i & 31;
        int n = b * W + r;
        if (n < N) {
            float ivn = inv[n];
            float v = b1[cc] + ivn * (tile[i] + xws[(size_t)n * HID1 + cc]);
            tile[i] = fmaxf(v, 0.f);
        }
        // rows with n >= N keep their zeros (never stored below)
    }
    __syncthreads();

    // hws = (h @ W2) * inv  -- 1024 outputs, 4 per thread
    for (int j = threadIdx.x; j < W * HID2; j += 256) {
        int r = j >> 4, cc = j & 15;
        int n = b * W + r;
        if (n >= N) continue;
        float acc = 0.f;
#pragma unroll
        for (int k = 0; k < HID1; ++k)
            acc += tile[r * HID1 + k] * sW2[k * HID2 + cc];
        hws[(size_t)n * HID2 + cc] = acc * inv[n];
    }
}

// Layer-2 aggregate: 64x16 LDS tile (4 KB), starts 0..15, stride 64, unroll 4.
__global__ __launch_bounds__(256) void agg2_k(const int* __restrict__ gCursor,
                                              const int* __restrict__ packed,
                                              const float* __restrict__ inv,
                                              const float* __restrict__ hws,
                                              const float* __restrict__ b2,
                                              float* __restrict__ out, int N) {
    __shared__ float tile[W * HID2];     // 4 KB
    int b = blockIdx.x;
    int start = b * CAP;
    int cnt = gCursor[b] - start;

    for (int i = threadIdx.x; i < W * HID2; i += 256) tile[i] = 0.f;
    __syncthreads();

    int lane = threadIdx.x & 63;
    int wv   = threadIdx.x >> 6;        // 0..3
    int c    = lane & 15;
    int q    = lane >> 4;               // 0..3
    for (int i = 4 * wv + q; i < cnt; i += 64) {
        int ib = i + 16, ic = i + 32, id = i + 48;
        bool vb = ib < cnt, vc = ic < cnt, vd = id < cnt;
        int ra = packed[start + i];
        int rb = packed[start + (vb ? ib : 0)];
        int rc = packed[start + (vc ? ic : 0)];
        int rd = packed[start + (vd ? id : 0)];
        float fa = hws[(size_t)(ra >> WSHIFT) * HID2 + c];
        float fb = hws[(size_t)(rb >> WSHIFT) * HID2 + c];
        float fc = hws[(size_t)(rc >> WSHIFT) * HID2 + c];
        float fd = hws[(size_t)(rd >> WSHIFT) * HID2 + c];
        atomicAdd(&tile[(ra & WMASK) * HID2 + c], fa);
        atomicAdd(&tile[(rb & WMASK) * HID2 + c], vb ? fb : 0.f);
        atomicAdd(&tile[(rc & WMASK) * HID2 + c], vc ? fc : 0.f);
        atomicAdd(&tile[(rd & WMASK) * HID2 + c], vd ? fd : 0.f);
    }
    __syncthreads();

    // out = b2 + inv[n]*(agg + hws_self)  -- FIX: no extra *inv on self
    for (int i = threadIdx.x; i < W * HID2; i += 256) {
        int r = i >> 4, cc = i & 15;
        int n = b * W + r;
        if (n < N) {
            float ivn = inv[n];
            out[(size_t)n * HID2 + cc] =
                b2[cc] + ivn * (tile[i] + hws[(size_t)n * HID2 + cc]);
        }
    }
}

// ---------------------------------------------------------------------------
extern "C" void kernel_launch(void* const* d_in, const int* in_sizes, int n_in,
                              void* d_out, int out_size, void* d_ws, size_t ws_size,
                              hipStream_t stream) {
    const float* x  = (const float*)d_in[0];
    const float* W1 = (const float*)d_in[1];
    const float* b1 = (const float*)d_in[2];
    const float* W2 = (const float*)d_in[3];
    const float* b2 = (const float*)d_in[4];
    const int*  e32 = (const int*)d_in[5];
    float* out = (float*)d_out;

    const int N = in_sizes[0] / IN_DIM;   // 100000
    const long E = in_sizes[5] / 2;       // 3200000
    const int B = (N + W - 1) >> WSHIFT;  // 1563

    // workspace layout: 256 B + 6.4 KB + 400 KB + 16.0 MB + 12.8 MB + 6.4 MB
    //                 = 35.6 MB
    char* ws = (char*)d_ws;
    int*   flag    = (int*)ws;                                  // 1
    int*   gCursor = (int*)(ws + 256);                          // B
    float* inv     = (float*)(gCursor + ((B + 63) / 64) * 64);  // N
    int*   packed  = (int*)(inv + ((N + 63) / 64) * 64);        // B*CAP
    float* xws     = (float*)(packed + (size_t)B * CAP);        // N*32
    float* hws     = xws + (size_t)N * HID1;                    // N*16 (no alias:
                                                                //  agg1 reads xws while writing hws)

    detect_fmt<<<1, 64, 0, stream>>>(e32, flag);
    init_cursor<<<(B + 255) / 256, 256, 0, stream>>>(gCursor, B);
    bin_fill<<<NB_FILL, 512, 0, stream>>>(e32, flag, gCursor, packed, E, B);
    deg_k<<<B, 256, 0, stream>>>(gCursor, packed, inv, N);

    gemm1<<<(N + 7) / 8, 256, 0, stream>>>(x, W1, inv, xws, N);
    agg1_k<<<B, 256, 0, stream>>>(gCursor, packed, inv, xws, b1, W2, hws, N);
    agg2_k<<<B, 256, 0, stream>>>(gCursor, packed, inv, hws, b2, out, N);
}